// Round 10
// baseline (39.323 us; speedup 1.0000x reference)
//
#include <hip/hip_runtime.h>

#define N_PED  8192
#define HID    128
#define NN     36
#define IPB    8             // i-rows per block
#define SLICES 64            // j-slices per block (one per 8-thread group)
#define BLOCK  512           // IPB * SLICES
#define JS     128           // j's per thread (8192/64)
#define HWW    10            // words/thread/array: 9 bin-words + 1 trash
#define NB     1024          // 8192 / IPB

// One batch = 2 pairs, non-atomic RMW, race-free by construction:
//  - pair0 -> array A, pair1 -> array B (never the same LDS word in-batch)
//  - single s_waitcnt lgkmcnt(0) between the reads and the adds: order-free
//    (R8's lgkmcnt(2) failed: write-retire is early, read-retire is late,
//     so a nonzero count cannot identify WHICH ops completed)
//  - write_X(batch n) -> read_X(batch n+1) same-address ordering is the
//    per-wave in-order LDS memory pipe (same guarantee compiler RMW uses;
//    validated by R4/R5 passing repeated replays).
__device__ __forceinline__ void rmw2(float p0x, float p0y, float p1x, float p1y,
                                     float xi4, float yi4, unsigned vone,
                                     unsigned baseA, unsigned baseB) {
    unsigned tA, iA, aA, vA, tB, iB, aB, vB;
    asm volatile(
        // interleaved bin math: A-chain and B-chain (independent -> ILP)
        "v_sub_f32 %[tA], %[p0x], %[xi4]\n\t"
        "v_sub_f32 %[iA], %[p0y], %[yi4]\n\t"
        "v_sub_f32 %[tB], %[p1x], %[xi4]\n\t"
        "v_sub_f32 %[iB], %[p1y], %[yi4]\n\t"
        "v_cvt_i32_f32 %[tA], %[tA]\n\t"
        "v_cvt_i32_f32 %[iA], %[iA]\n\t"
        "v_cvt_i32_f32 %[tB], %[tB]\n\t"
        "v_cvt_i32_f32 %[iB], %[iB]\n\t"
        "v_add_u32 %[tA], -1, %[tA]\n\t"
        "v_add_u32 %[iA], -1, %[iA]\n\t"
        "v_add_u32 %[tB], -1, %[tB]\n\t"
        "v_add_u32 %[iB], -1, %[iB]\n\t"
        "v_max_u32 %[aA], %[tA], %[iA]\n\t"
        "v_max_u32 %[aB], %[tB], %[iB]\n\t"
        "v_mad_u32_u24 %[tA], %[tA], 6, %[iA]\n\t"   // binA
        "v_mad_u32_u24 %[tB], %[tB], 6, %[iB]\n\t"   // binB
        "v_cmp_gt_u32 vcc, 6, %[aA]\n\t"
        "v_lshrrev_b32 %[aA], 2, %[tA]\n\t"
        "v_cndmask_b32 %[aA], 9, %[aA], vcc\n\t"     // wA (9 = trash)
        "v_cmp_gt_u32 vcc, 6, %[aB]\n\t"
        "v_lshrrev_b32 %[aB], 2, %[tB]\n\t"
        "v_cndmask_b32 %[aB], 9, %[aB], vcc\n\t"     // wB
        "v_lshlrev_b32 %[iA], 3, %[tA]\n\t"
        "v_lshlrev_b32 %[iA], %[iA], %[one]\n\t"     // incA = 1<<((bin*8)&31)
        "v_lshlrev_b32 %[iB], 3, %[tB]\n\t"
        "v_lshlrev_b32 %[iB], %[iB], %[one]\n\t"     // incB
        "v_lshl_add_u32 %[aA], %[aA], 11, %[bA]\n\t" // addrA = baseA + wA*2048
        "v_lshl_add_u32 %[aB], %[aB], 11, %[bB]\n\t" // addrB
        // RMW: both reads, ONE unambiguous wait, adds, writes
        "ds_read_b32 %[vA], %[aA]\n\t"
        "ds_read_b32 %[vB], %[aB]\n\t"
        "s_waitcnt lgkmcnt(0)\n\t"
        "v_add_u32 %[vA], %[vA], %[iA]\n\t"
        "v_add_u32 %[vB], %[vB], %[iB]\n\t"
        "ds_write_b32 %[aA], %[vA]\n\t"
        "ds_write_b32 %[aB], %[vB]\n\t"
        : [tA]"=&v"(tA), [iA]"=&v"(iA), [aA]"=&v"(aA), [vA]"=&v"(vA),
          [tB]"=&v"(tB), [iB]"=&v"(iB), [aB]"=&v"(aB), [vB]"=&v"(vB)
        : [p0x]"v"(p0x), [p0y]"v"(p0y), [p1x]"v"(p1x), [p1y]"v"(p1y),
          [xi4]"v"(xi4), [yi4]"v"(yi4), [one]"v"(vone),
          [bA]"v"(baseA), [bB]"v"(baseB)
        : "vcc");
}

__global__ __launch_bounds__(BLOCK, 6) void pool_kernel(
    const float* __restrict__ obs2_g,   // [8192][2]
    const float* __restrict__ Wg,       // [128][36] row-major
    const float* __restrict__ bias,     // [128]
    float* __restrict__ out)            // [8192][128]
{
    __shared__ unsigned s_hA[HWW * BLOCK];         // 20,480 B
    __shared__ unsigned s_hB[HWW * BLOCK];         // 20,480 B
    __shared__ float    s_rgrid[IPB][NN];          //  1,152 B
    __shared__ unsigned s_wsel[IPB];               //     32 B
    // 42,176 B -> 3 blocks/CU (24 waves/CU, 6 waves/SIMD)

    const int tid = threadIdx.x;
    const int bid = blockIdx.x;

    // ---- Phase 0: zero histograms (bank-striped: bank = tid%32, 2-way = free)
    #pragma unroll
    for (int k = 0; k < HWW; ++k) {
        s_hA[tid + k * BLOCK] = 0u;
        s_hB[tid + k * BLOCK] = 0u;
    }

    // ---- per-thread row setup
    const int il    = tid & (IPB - 1);
    const int slice = tid >> 3;                    // 0..63
    const int i     = bid * IPB + il;

    const float2 pi = ((const float2*)obs2_g)[i];
    const float  xi4 = pi.x - 4.0f;
    const float  yi4 = pi.y - 4.0f;

    // self-pair bin via IDENTICAL arithmetic (handles fl(xi - fl(xi-4)) != 4)
    if (tid < IPB) {
        float dx = pi.x - xi4;
        float dy = pi.y - yi4;
        unsigned u1 = (unsigned)((int)dx) - 1u;
        unsigned u2 = (unsigned)((int)dy) - 1u;
        bool ok = (u1 < 6u) & (u2 < 6u);           // false iff NaN/inf row
        s_wsel[il] = ok ? (u1 * 6u + u2) : 255u;
    }
    __syncthreads();

    // ---- Phase 1: pairwise occupancy histogram (batched asm RMW)
    const unsigned vone  = 1u;
    const unsigned baseA = (unsigned)(uintptr_t)&s_hA[tid];   // LDS byte addr
    const unsigned baseB = (unsigned)(uintptr_t)&s_hB[tid];

    #define PAIR8(r0, r1, r2, r3) do {                              \
        rmw2(r0.x, r0.y, r0.z, r0.w, xi4, yi4, vone, baseA, baseB); \
        rmw2(r1.x, r1.y, r1.z, r1.w, xi4, yi4, vone, baseA, baseB); \
        rmw2(r2.x, r2.y, r2.z, r2.w, xi4, yi4, vone, baseA, baseB); \
        rmw2(r3.x, r3.y, r3.z, r3.w, xi4, yi4, vone, baseA, baseB); \
    } while (0)

    {
        const float4* jp = (const float4*)obs2_g + slice * (JS / 2);  // 64 float4
        float4 a0 = jp[0], a1 = jp[1], a2 = jp[2], a3 = jp[3];
        float4 b0 = jp[4], b1 = jp[5], b2 = jp[6], b3 = jp[7];
        jp += 8;
        #pragma unroll 1
        for (int it = 0; it < 7; ++it) {           // 7 x 16 + 16 = 128 pairs
            PAIR8(a0, a1, a2, a3);
            a0 = jp[0]; a1 = jp[1]; a2 = jp[2]; a3 = jp[3];
            PAIR8(b0, b1, b2, b3);
            b0 = jp[4]; b1 = jp[5]; b2 = jp[6]; b3 = jp[7];
            jp += 8;
        }
        PAIR8(a0, a1, a2, a3);
        PAIR8(b0, b1, b2, b3);
    }
    #undef PAIR8

    // asm DS ops are invisible to the compiler's waitcnt tracking:
    // drain before the barrier so all writes are LDS-visible.
    asm volatile("s_waitcnt lgkmcnt(0)" ::: "memory");
    __syncthreads();

    // ---- Phase 2: byte-wise reduce over 64 slices x 2 arrays (72 tasks)
    if (tid < IPB * 9) {                           // 72
        const int ril = tid & (IPB - 1);
        const int w   = tid >> 3;                  // 0..8
        unsigned lo = 0u, hi = 0u;                 // 2x u16 lanes each (max 8192)
        #pragma unroll 8
        for (int sl = 0; sl < SLICES; ++sl) {
            unsigned t = sl * IPB + ril;
            unsigned a = s_hA[(w << 9) + t];
            unsigned b = s_hB[(w << 9) + t];
            lo += (a & 0x00FF00FFu) + (b & 0x00FF00FFu);
            hi += ((a >> 8) & 0x00FF00FFu) + ((b >> 8) & 0x00FF00FFu);
        }
        unsigned s0 = lo & 0xFFFFu;
        unsigned s1 = hi & 0xFFFFu;
        unsigned s2 = lo >> 16;
        unsigned s3 = hi >> 16;
        const unsigned sel  = s_wsel[ril];
        const unsigned base = (unsigned)(w * 4);
        s0 -= (sel == base + 0u);
        s1 -= (sel == base + 1u);
        s2 -= (sel == base + 2u);
        s3 -= (sel == base + 3u);
        s_rgrid[ril][base + 0] = (float)s0;
        s_rgrid[ril][base + 1] = (float)s1;
        s_rgrid[ril][base + 2] = (float)s2;
        s_rgrid[ril][base + 3] = (float)s3;
    }
    __syncthreads();

    // ---- Phase 3: fused GEMM  out[i][h] = sum_k grid[i][k]*W[h][k] + b[h]
    const int h  = tid & (HID - 1);                // 0..127
    const int r0 = tid >> 7;                       // 0..3 (wave-pair uniform)
    const float4* W4 = (const float4*)Wg;          // [128][9] float4

    const float bh = bias[h];
    float acc0 = bh, acc1 = bh;

    #pragma unroll
    for (int k4 = 0; k4 < 9; ++k4) {
        float4 w4 = W4[h * 9 + k4];
        float4 g0 = *(const float4*)&s_rgrid[r0    ][k4 * 4];
        float4 g1 = *(const float4*)&s_rgrid[r0 + 4][k4 * 4];
        acc0 += g0.x * w4.x + g0.y * w4.y + g0.z * w4.z + g0.w * w4.w;
        acc1 += g1.x * w4.x + g1.y * w4.y + g1.z * w4.z + g1.w * w4.w;
    }

    const int obase = bid * IPB;
    out[(obase + r0    ) * HID + h] = acc0;
    out[(obase + r0 + 4) * HID + h] = acc1;
}

extern "C" void kernel_launch(void* const* d_in, const int* in_sizes, int n_in,
                              void* d_out, int out_size, void* d_ws, size_t ws_size,
                              hipStream_t stream) {
    // inputs: 0=hidden_state (unused), 1=obs1 (unused), 2=obs2, 3=W, 4=b
    const float* obs2 = (const float*)d_in[2];
    const float* W    = (const float*)d_in[3];
    const float* b    = (const float*)d_in[4];
    float* out        = (float*)d_out;
    (void)in_sizes; (void)n_in; (void)out_size; (void)d_ws; (void)ws_size;

    hipLaunchKernelGGL(pool_kernel, dim3(NB), dim3(BLOCK), 0, stream,
                       obs2, W, b, out);
}